// Round 6
// baseline (126.321 us; speedup 1.0000x reference)
//
#include <hip/hip_runtime.h>

typedef float f4 __attribute__((ext_vector_type(4)));

#define BB   16
#define NN   512
#define DIN  256
#define COUT 32
#define CCS  48
#define HH   256
#define WWG  256
#define HW   (HH * WWG)          // 65536 = 1<<16
#define CTOT (CCS + COUT)        // 80

#define NGEMM   1024             // BB*NN/8 GEMM blocks
#define NWIN    1
#define FILL0   (NGEMM + NWIN)
#define NFILL   (BB * CTOT * HW / 4 / 256)   // 81920 fill blocks (1 f4/thread)

// ---------------------------------------------------------------------------
// Fused kernel:
//  blocks [0,1024):  proj = emb·W + b (LDS-free; W via L1; 4-way accumulators)
//  block  1024:      winner map: init touched cells to -1, __syncthreads,
//                    atomicMax(flat entity index) — max == last-write-wins.
//  blocks [1025,..): fill, EXACT R2 access pattern: 1 f4/thread, out index is
//                    globally linear in thread id, per-block-uniform channel.
// ---------------------------------------------------------------------------
__global__ __launch_bounds__(256) void k_fused(
        const float* __restrict__ emb, const float* __restrict__ Wm,
        const float* __restrict__ bias, const int* __restrict__ loc,
        const float* __restrict__ sp,
        float* __restrict__ proj, int* __restrict__ winner,
        float* __restrict__ out) {
    int tid = threadIdx.x;
    int bx  = blockIdx.x;

    if (bx >= FILL0) {
        // ---- fill ----
        int idx  = (bx - FILL0) * 256 + tid;   // global out f4 index, 0..20971519
        int pix4 = idx & 16383;
        int t    = idx >> 14;                  // b*80 + ch, uniform per block
        int b    = t / CTOT;
        int ch   = t - b * CTOT;
        f4* o = (f4*)out + idx;                // out is linear in idx
        if (ch < CCS) {
            const f4* s = (const f4*)sp + (((size_t)(t - b * COUT)) << 14) + pix4;
            f4 v = __builtin_nontemporal_load(s);
            __builtin_nontemporal_store(v, o);
        } else {
            __builtin_nontemporal_store((f4)(0.0f), o);
        }
        return;
    }
    if (bx < NGEMM) {
        // ---- proj GEMM (no LDS) ----
        int c = tid & 31;
        int r = tid >> 5;                      // 0..7
        int row = bx * 8 + r;                  // flat entity index, 0..8191
        const f4* e4 = (const f4*)(emb + (size_t)row * DIN);
        const float* wc = Wm + c;
        float a0 = 0.f, a1 = 0.f, a2 = 0.f, a3 = 0.f;
        #pragma unroll 4
        for (int d4 = 0; d4 < DIN / 4; ++d4) {
            f4 ev = e4[d4];
            int d = d4 * 4;
            a0 += ev.x * wc[(size_t)(d + 0) * COUT];
            a1 += ev.y * wc[(size_t)(d + 1) * COUT];
            a2 += ev.z * wc[(size_t)(d + 2) * COUT];
            a3 += ev.w * wc[(size_t)(d + 3) * COUT];
        }
        proj[(size_t)row * COUT + c] = (a0 + a1) + (a2 + a3) + bias[c];
        return;
    }
    // ---- winner map (single block; touched cells only — replay-safe) ----
    #pragma unroll
    for (int k = 0; k < BB * NN / 256; ++k) {
        int i = k * 256 + tid;
        int b = i >> 9;
        int h = loc[2 * i + 0];
        int w = loc[2 * i + 1];
        winner[b * HW + h * WWG + w] = -1;
    }
    __syncthreads();
    #pragma unroll
    for (int k = 0; k < BB * NN / 256; ++k) {
        int i = k * 256 + tid;
        int b = i >> 9;
        int h = loc[2 * i + 0];
        int w = loc[2 * i + 1];
        atomicMax(&winner[b * HW + h * WWG + w], i);
    }
}

// ---------------------------------------------------------------------------
// Winning entity writes its 32-channel proj vector to out[b, 48+c, h, w].
// ---------------------------------------------------------------------------
__global__ __launch_bounds__(256) void k_scatter(
        const float* __restrict__ proj, const int* __restrict__ loc,
        const int* __restrict__ winner, float* __restrict__ out) {
    int t = blockIdx.x * 256 + threadIdx.x;
    int c = t & 31;
    int i = t >> 5;                            // flat entity index
    int b = i >> 9;
    int h = loc[2 * i + 0];
    int w = loc[2 * i + 1];
    int cell = b * HW + h * WWG + w;
    if (winner[cell] != i) return;             // last-write-wins (max flat index)
    out[((size_t)(b * CTOT + CCS + c) << 16) + (size_t)h * WWG + w] =
        proj[(size_t)i * COUT + c];
}

extern "C" void kernel_launch(void* const* d_in, const int* in_sizes, int n_in,
                              void* d_out, int out_size, void* d_ws, size_t ws_size,
                              hipStream_t stream) {
    const float* sp   = (const float*)d_in[0];   // [16,48,256,256]
    const float* emb  = (const float*)d_in[1];   // [16,512,256]
    const float* Wm   = (const float*)d_in[2];   // [256,32]
    const float* bias = (const float*)d_in[3];   // [32]
    const int*   loc  = (const int*)d_in[4];     // [16,512,2]
    float* out = (float*)d_out;                  // [16,80,256,256]

    float* proj   = (float*)d_ws;                                     // 1 MB
    int*   winner = (int*)((char*)d_ws + (size_t)BB * NN * COUT * 4); // 4 MB

    hipLaunchKernelGGL(k_fused, dim3(FILL0 + NFILL), dim3(256), 0, stream,
                       emb, Wm, bias, loc, sp, proj, winner, out);

    hipLaunchKernelGGL(k_scatter, dim3(BB * NN * COUT / 256), dim3(256), 0, stream,
                       proj, loc, winner, out);
}